// Round 12
// baseline (494.254 us; speedup 1.0000x reference)
//
#include <hip/hip_runtime.h>

#define NHOST 32768
#define MINF  65536
#define TSTEPS 365
#define DELTA_ 5
#define KMAX  6            // slots per (host,sublane); 4 sublanes -> supports cnt <= 24

// Constants from reference
#define C_E_STAR      0.032f
#define C_S_IMM       0.14f
#define C_S_INFTY     0.049f
#define C_X_H_STAR    97.3f
#define C_X_NU_STAR   4.8f
#define C_X_P_STAR    1514.4f
#define C_X_Y_STAR    3.5f
#define C_ALPHA_M     0.9f
#define C_ALPHA_M_ST  2.53f
#define C_GAMMA_P     2.04f
#define C_SIGMA_0     0.8124038404635961f  // sqrt(0.66)
#define C_LN2         0.6931471805599453f

// ---------------- preprocessing kernels ----------------

__global__ void initK(int* __restrict__ cnt, int* __restrict__ cursor) {
    int i = blockIdx.x * blockDim.x + threadIdx.x;
    if (i < NHOST) { cnt[i] = 0; cursor[i] = 0; }
}

__global__ void histK(const int* __restrict__ idx, int* __restrict__ cnt) {
    int j = blockIdx.x * blockDim.x + threadIdx.x;
    if (j < MINF) atomicAdd(&cnt[idx[j]], 1);
}

// Exclusive scan of cnt[NHOST] -> start[NHOST]; single block of 1024 threads.
__global__ __launch_bounds__(1024) void scanK(const int* __restrict__ cnt,
                                              int* __restrict__ start) {
    __shared__ int sh[1024];
    int tid = threadIdx.x;
    int base = tid * 32;
    int s = 0;
    #pragma unroll
    for (int k = 0; k < 32; ++k) s += cnt[base + k];
    sh[tid] = s;
    __syncthreads();
    for (int o = 1; o < 1024; o <<= 1) {
        int v = 0;
        if (tid >= o) v = sh[tid - o];
        __syncthreads();
        sh[tid] += v;
        __syncthreads();
    }
    int run = sh[tid] - s;
    #pragma unroll
    for (int k = 0; k < 32; ++k) {
        start[base + k] = run;
        run += cnt[base + k];
    }
}

__global__ void scatterK(const int* __restrict__ idx,
                         const float* __restrict__ tau0,
                         const float* __restrict__ tau_max,
                         const int* __restrict__ start,
                         int* __restrict__ cursor,
                         int* __restrict__ slotJ,
                         float* __restrict__ slotT0,
                         float* __restrict__ slotT1) {
    int j = blockIdx.x * blockDim.x + threadIdx.x;
    if (j >= MINF) return;
    int h = idx[j];
    int p = start[h] + atomicAdd(&cursor[h], 1);
    slotJ[p]  = j;
    slotT0[p] = tau0[j];
    slotT1[p] = tau_max[j];
}

// ---------------- main kernel: round-6 body + block-index permutation -------
// SINGLE change vs the 65 us round-6 kernel: blocks are remapped by
// pi(b) = b<256 ? 2b : 1023-2b, so blocks b and b+256 (which land on the
// same CU under round-robin dispatch) carry complementary workloads:
// iters(pi(c)) + iters(pi(c+256)) ~ const. Per-wave work is unchanged
// (each wave still runs only its own [tstart, 365) range) - this conserves
// total wave-iters, unlike round 8's pairing which doubled them.

__global__ __launch_bounds__(256) void mainK(const float* __restrict__ EIR,
                                             const float* __restrict__ log_d,
                                             const int* __restrict__ offsets,
                                             const float* __restrict__ eps,
                                             const int* __restrict__ start,
                                             const int* __restrict__ cnt,
                                             const int* __restrict__ slotJ,
                                             const float* __restrict__ slotT0,
                                             const float* __restrict__ slotT1,
                                             float* __restrict__ out) {
    __shared__ float sEff[TSTEPS];
    __shared__ float sDm[TSTEPS];
    for (int k = threadIdx.x; k < TSTEPS; k += blockDim.x) {
        float tf  = (float)(k * DELTA_);
        float age = fminf(tf, 7300.0f) * (1.0f / 365.0f);
        float bs  = 2.009715297378839e-1f +
                    age * (1.7984405384216584e-1f +
                    age * (-2.121587990857579e-2f +
                    age * (1.3554013908681017e-3f +
                    age * (-2.847697353524861e-5f))));
        sEff[k] = EIR[k % 73] * bs * (1.0f / 1.63f);
        sDm[k]  = 1.0f - C_ALPHA_M * expf(-(tf / 365.0f / C_ALPHA_M_ST) * C_LN2);
    }
    __syncthreads();

    // load-balance permutation (the ONLY change vs round 6)
    int b  = blockIdx.x;
    int pb = (b < 256) ? (2 * b) : (1023 - 2 * b);
    int tid = pb * 256 + threadIdx.x;
    int h   = tid >> 2;
    int sub = tid & 3;

    int off = offsets[h];
    int ch  = cnt[h];
    int myCnt = (ch > sub) ? ((ch - sub + 3) >> 2) : 0;
    if (myCnt > KMAX) myCnt = KMAX;          // P(cnt>24) ~ 1e-14: accept
    int base = start[h] + sub;
    float ld = log_d[h] + 1e-10f;            // log_d_inf + ln_yG (constant)

    int   J[KMAX];
    float T0[KMAX], T1[KMAX], Xy[KMAX], ec[KMAX];
    #pragma unroll
    for (int k = 0; k < KMAX; ++k) {
        Xy[k] = 0.0f; ec[k] = 0.0f; J[k] = 0;
        T0[k] = 1e30f; T1[k] = -1e30f;       // defaults -> never active
        if (k < myCnt) {
            int p = base + 4 * k;
            J[k]  = slotJ[p];
            T0[k] = slotT0[p];
            T1[k] = slotT1[p];
        }
    }

    int tstart = (off + DELTA_ - 1) / DELTA_;   // first t with t*DELTA >= off
    float Xp = 0.0f, Xh = 0.0f, Ylast = 0.0f;

    // prologue prefetch for t = tstart
    if (tstart < TSTEPS) {
        float tf0 = (float)(tstart * DELTA_);
        #pragma unroll
        for (int k = 0; k < KMAX; ++k)
            if (T0[k] <= tf0 && T1[k] > tf0)
                ec[k] = eps[(size_t)tstart * MINF + J[k]];
    }

    for (int t = tstart; t < TSTEPS; ++t) {
        float tf  = (float)(t * DELTA_);
        int   rel = t - tstart;                 // == clip((t*5-off)//5, 0, 364)
        float E   = sEff[rel];
        float Dm  = sDm[rel];

        // prefetch eps for t+1 (hides L3 latency under this iteration's VALU)
        float en[KMAX];
        #pragma unroll
        for (int k = 0; k < KMAX; ++k) en[k] = 0.0f;
        if (t < TSTEPS - 1) {
            float tf2 = tf + (float)DELTA_;
            #pragma unroll
            for (int k = 0; k < KMAX; ++k)
                if (T0[k] <= tf2 && T1[k] > tf2)
                    en[k] = eps[(size_t)(t + 1) * MINF + J[k]];
        }

        // host-state (computed redundantly by the quad's 4 lanes)
        float S1    = C_S_INFTY + (1.0f - C_S_INFTY) / (1.0f + E * (1.0f / C_E_STAR));
        float p204  = __powf(Xp * (1.0f / C_X_P_STAR), C_GAMMA_P);  // 0^2.04 -> 0
        float S2    = C_S_IMM + (1.0f - C_S_IMM) / (1.0f + p204);
        float hstar = S1 * S2 * E;
        float sigy  = C_SIGMA_0 * rsqrtf(1.0f + Xh * (1.0f / C_X_NU_STAR));
        float coef  = Dm / (1.0f + Xh * (1.0f / C_X_H_STAR));

        float ysum = 0.0f;
        float yk[KMAX];
        bool  ak[KMAX];
        #pragma unroll
        for (int k = 0; k < KMAX; ++k) {
            bool  act = (T0[k] <= tf) & (T1[k] > tf);
            float Dy  = 1.0f / (1.0f + Xy[k] * (1.0f / C_X_Y_STAR));
            float y   = act ? __expf(Dy * coef * ld + sigy * ec[k]) : 0.0f;
            ak[k] = act; yk[k] = y; ysum += y;
        }
        // quad (per-host) reduction
        float Ys = ysum + __shfl_xor(ysum, 1, 64);
        Ys += __shfl_xor(Ys, 2, 64);

        #pragma unroll
        for (int k = 0; k < KMAX; ++k)
            if (ak[k]) Xy[k] += Ys - yk[k];     // X_y += (Y - y) while active

        Xp += E; Xh += hstar; Ylast = Ys;

        #pragma unroll
        for (int k = 0; k < KMAX; ++k) ec[k] = en[k];
    }

    if (sub == 0) {
        out[h] = Ylast;                  // Y at final step
        out[NHOST + MINF + h] = Xh;      // X_h
    }
    #pragma unroll
    for (int k = 0; k < KMAX; ++k)
        if (k < myCnt) out[NHOST + J[k]] = Xy[k];   // X_y scattered to original j
}

// ---------------- launch ----------------

extern "C" void kernel_launch(void* const* d_in, const int* in_sizes, int n_in,
                              void* d_out, int out_size, void* d_ws, size_t ws_size,
                              hipStream_t stream) {
    const float* EIR     = (const float*)d_in[0];
    const float* log_d   = (const float*)d_in[1];
    const float* tau0    = (const float*)d_in[2];
    const float* tau_max = (const float*)d_in[3];
    const float* eps     = (const float*)d_in[4];
    const int*   idx     = (const int*)d_in[5];
    const int*   offsets = (const int*)d_in[6];
    float* out = (float*)d_out;

    char* ws = (char*)d_ws;
    int*   cnt    = (int*)ws;    ws += NHOST * sizeof(int);
    int*   start  = (int*)ws;    ws += NHOST * sizeof(int);
    int*   cursor = (int*)ws;    ws += NHOST * sizeof(int);
    int*   slotJ  = (int*)ws;    ws += MINF * sizeof(int);
    float* slotT0 = (float*)ws;  ws += MINF * sizeof(float);
    float* slotT1 = (float*)ws;  ws += MINF * sizeof(float);

    initK<<<NHOST / 256, 256, 0, stream>>>(cnt, cursor);
    histK<<<MINF / 256, 256, 0, stream>>>(idx, cnt);
    scanK<<<1, 1024, 0, stream>>>(cnt, start);
    scatterK<<<MINF / 256, 256, 0, stream>>>(idx, tau0, tau_max, start, cursor,
                                             slotJ, slotT0, slotT1);
    mainK<<<(NHOST * 4) / 256, 256, 0, stream>>>(EIR, log_d, offsets, eps,
                                                 start, cnt, slotJ, slotT0, slotT1,
                                                 out);
}

// Round 13
// 489.655 us; speedup vs baseline: 1.0094x; 1.0094x over previous
//
#include <hip/hip_runtime.h>

#define NHOST 32768
#define MINF  65536
#define TSTEPS 365
#define DELTA_ 5
#define KMAX  6            // slots per (host,sublane); 4 sublanes -> supports cnt <= 24

// Constants from reference
#define C_E_STAR      0.032f
#define C_S_IMM       0.14f
#define C_S_INFTY     0.049f
#define C_X_H_STAR    97.3f
#define C_X_NU_STAR   4.8f
#define C_X_P_STAR    1514.4f
#define C_X_Y_STAR    3.5f
#define C_ALPHA_M     0.9f
#define C_ALPHA_M_ST  2.53f
#define C_GAMMA_P     2.04f
#define C_SIGMA_0     0.8124038404635961f  // sqrt(0.66)
#define C_LN2         0.6931471805599453f

// ---------------- preprocessing kernels ----------------

__global__ void initK(int* __restrict__ cnt, int* __restrict__ cursor) {
    int i = blockIdx.x * blockDim.x + threadIdx.x;
    if (i < NHOST) { cnt[i] = 0; cursor[i] = 0; }
}

__global__ void histK(const int* __restrict__ idx, int* __restrict__ cnt) {
    int j = blockIdx.x * blockDim.x + threadIdx.x;
    if (j < MINF) atomicAdd(&cnt[idx[j]], 1);
}

// Exclusive scan of cnt[NHOST] -> start[NHOST]; single block of 1024 threads.
__global__ __launch_bounds__(1024) void scanK(const int* __restrict__ cnt,
                                              int* __restrict__ start) {
    __shared__ int sh[1024];
    int tid = threadIdx.x;
    int base = tid * 32;
    int s = 0;
    #pragma unroll
    for (int k = 0; k < 32; ++k) s += cnt[base + k];
    sh[tid] = s;
    __syncthreads();
    for (int o = 1; o < 1024; o <<= 1) {
        int v = 0;
        if (tid >= o) v = sh[tid - o];
        __syncthreads();
        sh[tid] += v;
        __syncthreads();
    }
    int run = sh[tid] - s;
    #pragma unroll
    for (int k = 0; k < 32; ++k) {
        start[base + k] = run;
        run += cnt[base + k];
    }
}

__global__ void scatterK(const int* __restrict__ idx,
                         const float* __restrict__ tau0,
                         const float* __restrict__ tau_max,
                         const int* __restrict__ start,
                         int* __restrict__ cursor,
                         int* __restrict__ slotJ,
                         float* __restrict__ slotT0,
                         float* __restrict__ slotT1) {
    int j = blockIdx.x * blockDim.x + threadIdx.x;
    if (j >= MINF) return;
    int h = idx[j];
    int p = start[h] + atomicAdd(&cursor[h], 1);
    slotJ[p]  = j;
    slotT0[p] = tau0[j];
    slotT1[p] = tau_max[j];
}

// ---------------- main kernel: round-6 body + block-index permutation -------
// SINGLE change vs the 65 us round-6 kernel: blocks are remapped by
// pi(b) = b<256 ? 2b : 1023-2b, so blocks b and b+256 (which land on the
// same CU under round-robin dispatch) carry complementary workloads:
// iters(pi(c)) + iters(pi(c+256)) ~ const. Per-wave work is unchanged
// (each wave still runs only its own [tstart, 365) range) - this conserves
// total wave-iters, unlike round 8's pairing which doubled them.
//
// NOTE round-12 run of this exact source measured 366 us with VALU-busy-time
// 7x the identical instruction stream's r6 measurement -> attributed to chip
// contention (acquire_s=96 at capacity), not to this code. Re-testing.

__global__ __launch_bounds__(256) void mainK(const float* __restrict__ EIR,
                                             const float* __restrict__ log_d,
                                             const int* __restrict__ offsets,
                                             const float* __restrict__ eps,
                                             const int* __restrict__ start,
                                             const int* __restrict__ cnt,
                                             const int* __restrict__ slotJ,
                                             const float* __restrict__ slotT0,
                                             const float* __restrict__ slotT1,
                                             float* __restrict__ out) {
    __shared__ float sEff[TSTEPS];
    __shared__ float sDm[TSTEPS];
    for (int k = threadIdx.x; k < TSTEPS; k += blockDim.x) {
        float tf  = (float)(k * DELTA_);
        float age = fminf(tf, 7300.0f) * (1.0f / 365.0f);
        float bs  = 2.009715297378839e-1f +
                    age * (1.7984405384216584e-1f +
                    age * (-2.121587990857579e-2f +
                    age * (1.3554013908681017e-3f +
                    age * (-2.847697353524861e-5f))));
        sEff[k] = EIR[k % 73] * bs * (1.0f / 1.63f);
        sDm[k]  = 1.0f - C_ALPHA_M * expf(-(tf / 365.0f / C_ALPHA_M_ST) * C_LN2);
    }
    __syncthreads();

    // load-balance permutation (the ONLY change vs round 6)
    int b  = blockIdx.x;
    int pb = (b < 256) ? (2 * b) : (1023 - 2 * b);
    int tid = pb * 256 + threadIdx.x;
    int h   = tid >> 2;
    int sub = tid & 3;

    int off = offsets[h];
    int ch  = cnt[h];
    int myCnt = (ch > sub) ? ((ch - sub + 3) >> 2) : 0;
    if (myCnt > KMAX) myCnt = KMAX;          // P(cnt>24) ~ 1e-14: accept
    int base = start[h] + sub;
    float ld = log_d[h] + 1e-10f;            // log_d_inf + ln_yG (constant)

    int   J[KMAX];
    float T0[KMAX], T1[KMAX], Xy[KMAX], ec[KMAX];
    #pragma unroll
    for (int k = 0; k < KMAX; ++k) {
        Xy[k] = 0.0f; ec[k] = 0.0f; J[k] = 0;
        T0[k] = 1e30f; T1[k] = -1e30f;       // defaults -> never active
        if (k < myCnt) {
            int p = base + 4 * k;
            J[k]  = slotJ[p];
            T0[k] = slotT0[p];
            T1[k] = slotT1[p];
        }
    }

    int tstart = (off + DELTA_ - 1) / DELTA_;   // first t with t*DELTA >= off
    float Xp = 0.0f, Xh = 0.0f, Ylast = 0.0f;

    // prologue prefetch for t = tstart
    if (tstart < TSTEPS) {
        float tf0 = (float)(tstart * DELTA_);
        #pragma unroll
        for (int k = 0; k < KMAX; ++k)
            if (T0[k] <= tf0 && T1[k] > tf0)
                ec[k] = eps[(size_t)tstart * MINF + J[k]];
    }

    for (int t = tstart; t < TSTEPS; ++t) {
        float tf  = (float)(t * DELTA_);
        int   rel = t - tstart;                 // == clip((t*5-off)//5, 0, 364)
        float E   = sEff[rel];
        float Dm  = sDm[rel];

        // prefetch eps for t+1 (hides L3 latency under this iteration's VALU)
        float en[KMAX];
        #pragma unroll
        for (int k = 0; k < KMAX; ++k) en[k] = 0.0f;
        if (t < TSTEPS - 1) {
            float tf2 = tf + (float)DELTA_;
            #pragma unroll
            for (int k = 0; k < KMAX; ++k)
                if (T0[k] <= tf2 && T1[k] > tf2)
                    en[k] = eps[(size_t)(t + 1) * MINF + J[k]];
        }

        // host-state (computed redundantly by the quad's 4 lanes)
        float S1    = C_S_INFTY + (1.0f - C_S_INFTY) / (1.0f + E * (1.0f / C_E_STAR));
        float p204  = __powf(Xp * (1.0f / C_X_P_STAR), C_GAMMA_P);  // 0^2.04 -> 0
        float S2    = C_S_IMM + (1.0f - C_S_IMM) / (1.0f + p204);
        float hstar = S1 * S2 * E;
        float sigy  = C_SIGMA_0 * rsqrtf(1.0f + Xh * (1.0f / C_X_NU_STAR));
        float coef  = Dm / (1.0f + Xh * (1.0f / C_X_H_STAR));

        float ysum = 0.0f;
        float yk[KMAX];
        bool  ak[KMAX];
        #pragma unroll
        for (int k = 0; k < KMAX; ++k) {
            bool  act = (T0[k] <= tf) & (T1[k] > tf);
            float Dy  = 1.0f / (1.0f + Xy[k] * (1.0f / C_X_Y_STAR));
            float y   = act ? __expf(Dy * coef * ld + sigy * ec[k]) : 0.0f;
            ak[k] = act; yk[k] = y; ysum += y;
        }
        // quad (per-host) reduction
        float Ys = ysum + __shfl_xor(ysum, 1, 64);
        Ys += __shfl_xor(Ys, 2, 64);

        #pragma unroll
        for (int k = 0; k < KMAX; ++k)
            if (ak[k]) Xy[k] += Ys - yk[k];     // X_y += (Y - y) while active

        Xp += E; Xh += hstar; Ylast = Ys;

        #pragma unroll
        for (int k = 0; k < KMAX; ++k) ec[k] = en[k];
    }

    if (sub == 0) {
        out[h] = Ylast;                  // Y at final step
        out[NHOST + MINF + h] = Xh;      // X_h
    }
    #pragma unroll
    for (int k = 0; k < KMAX; ++k)
        if (k < myCnt) out[NHOST + J[k]] = Xy[k];   // X_y scattered to original j
}

// ---------------- launch ----------------

extern "C" void kernel_launch(void* const* d_in, const int* in_sizes, int n_in,
                              void* d_out, int out_size, void* d_ws, size_t ws_size,
                              hipStream_t stream) {
    const float* EIR     = (const float*)d_in[0];
    const float* log_d   = (const float*)d_in[1];
    const float* tau0    = (const float*)d_in[2];
    const float* tau_max = (const float*)d_in[3];
    const float* eps     = (const float*)d_in[4];
    const int*   idx     = (const int*)d_in[5];
    const int*   offsets = (const int*)d_in[6];
    float* out = (float*)d_out;

    char* ws = (char*)d_ws;
    int*   cnt    = (int*)ws;    ws += NHOST * sizeof(int);
    int*   start  = (int*)ws;    ws += NHOST * sizeof(int);
    int*   cursor = (int*)ws;    ws += NHOST * sizeof(int);
    int*   slotJ  = (int*)ws;    ws += MINF * sizeof(int);
    float* slotT0 = (float*)ws;  ws += MINF * sizeof(float);
    float* slotT1 = (float*)ws;  ws += MINF * sizeof(float);

    initK<<<NHOST / 256, 256, 0, stream>>>(cnt, cursor);
    histK<<<MINF / 256, 256, 0, stream>>>(idx, cnt);
    scanK<<<1, 1024, 0, stream>>>(cnt, start);
    scatterK<<<MINF / 256, 256, 0, stream>>>(idx, tau0, tau_max, start, cursor,
                                             slotJ, slotT0, slotT1);
    mainK<<<(NHOST * 4) / 256, 256, 0, stream>>>(EIR, log_d, offsets, eps,
                                                 start, cnt, slotJ, slotT0, slotT1,
                                                 out);
}